// Round 4
// baseline (156.320 us; speedup 1.0000x reference)
//
#include <hip/hip_runtime.h>
#include <hip/hip_bf16.h>
#include <cmath>

// GRU cell fused, round 4: two-stage design.
//  K1 (gru_gemm1): 256 uniform blocks (32m x 8n), m201-style 256x256 GEMM,
//     BK=64, 8 waves (2m x 4n), 4-phase interleave per K-tile, counted vmcnt(8).
//     flavor z (j<4): z=sigmoid(gate1), c=In@Wc ; flavor r (j>=4): r=sigmoid, hc=Hx@Whc.
//  K2 (gru_final): elementwise out = (1-z)*hx + z*tanh(c + bc + r*(hc + bhc)).
// ws (ushort elems):
//  wsIn  @0          [32 mt][16 kt][256x64 swz]  = 8,388,608
//  wsHx  @8,388,608  same                        = 8,388,608
//  wsW   @16,777,216 [8 j][48 kt][256x64 swz]    = 6,291,456
//  actZ  @23,068,672  frag-linear bf16           = 8,388,608
//  actR  @31,457,280
//  actC  @39,845,888
//  actH  @48,234,496   (end 56,623,104 elems = 113,246,208 B)

typedef __attribute__((ext_vector_type(8))) short bf16x8;
typedef __attribute__((ext_vector_type(4))) float f32x4;
typedef unsigned int u32;

typedef const __attribute__((address_space(1))) u32 gu32;
typedef __attribute__((address_space(3))) u32 su32;

__device__ __forceinline__ unsigned short f2bf(float f) {
  union { float f; u32 u; } v; v.f = f;
  u32 u = v.u;
  u += 0x7FFFu + ((u >> 16) & 1u);   // RTNE
  return (unsigned short)(u >> 16);
}
__device__ __forceinline__ float bfu(u32 w) {
  union { u32 u; float f; } c; c.u = (w & 0xffffu) << 16; return c.f;
}
__device__ __forceinline__ void gload16(void* ldsp, const void* gp) {
  __builtin_amdgcn_global_load_lds((gu32*)gp, (su32*)ldsp, 16, 0, 0);
}
__device__ __forceinline__ float sigmf(float x) { return 1.0f / (1.0f + __expf(-x)); }

// ================= prepass: fp32 -> bf16 pre-swizzled images =================
__global__ __launch_bounds__(256) void cvt2(
    const float* __restrict__ In, const float* __restrict__ Hx,
    const float* __restrict__ Wih, const float* __restrict__ Whh,
    const float* __restrict__ Wc,  const float* __restrict__ Whc,
    unsigned short* __restrict__ wsIn, unsigned short* __restrict__ wsHx,
    unsigned short* __restrict__ wsW)
{
  int bid = blockIdx.x;
  if (bid < 8192) {
    int gid = bid * 256 + threadIdx.x;      // 2 * 2^20 16B-slots
    const float* src; unsigned short* dst; int idx;
    if (gid < (1 << 20)) { src = In; dst = wsIn; idx = gid; }
    else                 { src = Hx; dst = wsHx; idx = gid - (1 << 20); }
    int m = idx >> 7, u = idx & 127;
    int kt = u >> 3, s = u & 7;
    const float4* p = (const float4*)(src + (size_t)m * 1024 + kt * 64 + s * 8);
    float4 a = p[0], b = p[1];
    int row = m & 255, mt = m >> 8;
    int sp = s ^ (row & 7);
    bf16x8 v;
    v[0] = (short)f2bf(a.x); v[1] = (short)f2bf(a.y); v[2] = (short)f2bf(a.z); v[3] = (short)f2bf(a.w);
    v[4] = (short)f2bf(b.x); v[5] = (short)f2bf(b.y); v[6] = (short)f2bf(b.z); v[7] = (short)f2bf(b.w);
    *(bf16x8*)(dst + (size_t)(mt * 16 + kt) * 16384 + row * 64 + sp * 8) = v;
  } else {
    int w = bid - 8192;                     // 0..3071
    int j = w / 384, rem = w % 384;
    int t = rem >> 3, s = rem & 7;
    int jj = j & 3, f = j >> 2;
    int row = threadIdx.x;                  // 0..255 (n within tile)
    const float* W; int NW, k0, ncol;
    if (t < 16)      { W = Wih; NW = 2048; k0 = t * 64 + s * 8;        ncol = f * 1024 + jj * 256 + row; }
    else if (t < 32) { W = Whh; NW = 2048; k0 = (t - 16) * 64 + s * 8; ncol = f * 1024 + jj * 256 + row; }
    else             { W = f ? Whc : Wc; NW = 1024; k0 = (t - 32) * 64 + s * 8; ncol = jj * 256 + row; }
    bf16x8 v;
    #pragma unroll
    for (int b = 0; b < 8; ++b) v[b] = (short)f2bf(W[(size_t)(k0 + b) * NW + ncol]);
    int sp = s ^ (row & 7);
    *(bf16x8*)(wsW + (size_t)(j * 48 + t) * 16384 + row * 64 + sp * 8) = v;
  }
}

// ================= K1: uniform 256x256 GEMM, 2 sequential acc phases =================
// LDS bytes: Abuf0 @0, Abuf1 @32768, Bbuf0 @65536, Bbuf1 @98304  (128 KB)
__global__ __launch_bounds__(512, 2) void gru_gemm1(
    const unsigned short* __restrict__ wsIn, const unsigned short* __restrict__ wsHx,
    const unsigned short* __restrict__ wsW,
    unsigned short* __restrict__ actZ, unsigned short* __restrict__ actR,
    unsigned short* __restrict__ actC, unsigned short* __restrict__ actH,
    const float* __restrict__ bih, const float* __restrict__ bhh)
{
  __shared__ unsigned short lds[65536];
  char* LB = (char*)lds;
  const int tid = threadIdx.x, lane = tid & 63, wave = tid >> 6;
  const int wm = wave >> 2, wn = wave & 3;          // 2m x 4n
  const int j = blockIdx.x & 7, i = blockIdx.x >> 3;
  const int jj = j & 3, f = j >> 2;                 // flavor: 0=z-side, 1=r-side
  const int r15 = lane & 15, q = lane >> 4, x7 = r15 & 7;

  int aOff[8][2], bOff[4][2];
  #pragma unroll
  for (int mr = 0; mr < 8; ++mr)
    #pragma unroll
    for (int kk = 0; kk < 2; ++kk)
      aOff[mr][kk] = (wm * 128 + mr * 16 + r15) * 128 + (((kk * 4 + q) ^ x7) << 4);
  #pragma unroll
  for (int nr = 0; nr < 4; ++nr)
    #pragma unroll
    for (int kk = 0; kk < 2; ++kk)
      bOff[nr][kk] = 65536 + (wn * 64 + nr * 16 + r15) * 128 + (((kk * 4 + q) ^ x7) << 4);

  const unsigned short* srcW  = wsW + (size_t)j * 48 * 16384;
  const unsigned short* srcA2 = f ? wsHx : wsIn;
  const int lo8 = lane * 8;

  auto aSrc = [&](int kt) -> const unsigned short* {
    const unsigned short* base; int t;
    if (kt < 16)      { base = wsIn;  t = kt; }
    else if (kt < 32) { base = wsHx;  t = kt - 16; }
    else              { base = srcA2; t = kt - 32; }
    return base + (size_t)(i * 16 + t) * 16384;
  };
  auto stageA = [&](int PB, int kt) {
    const unsigned short* s = aSrc(kt);
    #pragma unroll
    for (int c = 0; c < 4; ++c)
      gload16(LB + PB + (wave * 4 + c) * 1024, s + (wave * 4 + c) * 512 + lo8);
  };
  auto stageB = [&](int PB, int kt) {
    const unsigned short* s = srcW + (size_t)kt * 16384;
    #pragma unroll
    for (int c = 0; c < 4; ++c)
      gload16(LB + 65536 + PB + (wave * 4 + c) * 1024, s + (wave * 4 + c) * 512 + lo8);
  };

  f32x4 acc[8][4];
  #pragma unroll
  for (int mr = 0; mr < 8; ++mr)
    #pragma unroll
    for (int nr = 0; nr < 4; ++nr) acc[mr][nr] = (f32x4)(0.0f);

  // ---------- one K-tile, 4 phases ----------
  #define MG(AF, BF, MRB, NRB)                                                      \
    __builtin_amdgcn_s_setprio(1);                                                  \
    _Pragma("unroll")                                                               \
    for (int mr_ = 0; mr_ < 4; ++mr_)                                               \
      _Pragma("unroll")                                                             \
      for (int nr_ = 0; nr_ < 2; ++nr_)                                             \
        _Pragma("unroll")                                                           \
        for (int kk_ = 0; kk_ < 2; ++kk_)                                           \
          acc[(MRB)+mr_][(NRB)+nr_] = __builtin_amdgcn_mfma_f32_16x16x32_bf16(      \
              AF[mr_][kk_], BF[nr_][kk_], acc[(MRB)+mr_][(NRB)+nr_], 0, 0, 0);      \
    __builtin_amdgcn_s_setprio(0);

  #define TILE(PB, KT, KTN)                                                         \
  {                                                                                 \
    bf16x8 a0[4][2], a1[4][2], b0[2][2], b1[2][2];                                  \
    _Pragma("unroll")                                                               \
    for (int mr_ = 0; mr_ < 4; ++mr_)                                               \
      _Pragma("unroll")                                                             \
      for (int kk_ = 0; kk_ < 2; ++kk_)                                             \
        a0[mr_][kk_] = *(const bf16x8*)(LB + (PB) + aOff[mr_][kk_]);                \
    _Pragma("unroll")                                                               \
    for (int nr_ = 0; nr_ < 2; ++nr_)                                               \
      _Pragma("unroll")                                                             \
      for (int kk_ = 0; kk_ < 2; ++kk_)                                             \
        b0[nr_][kk_] = *(const bf16x8*)(LB + (PB) + bOff[nr_][kk_]);                \
    MG(a0, b0, 0, 0)                                                                \
    _Pragma("unroll")                                                               \
    for (int nr_ = 0; nr_ < 2; ++nr_)                                               \
      _Pragma("unroll")                                                             \
      for (int kk_ = 0; kk_ < 2; ++kk_)                                             \
        b1[nr_][kk_] = *(const bf16x8*)(LB + (PB) + bOff[nr_ + 2][kk_]);            \
    MG(a0, b1, 0, 2)                                                                \
    _Pragma("unroll")                                                               \
    for (int mr_ = 0; mr_ < 4; ++mr_)                                               \
      _Pragma("unroll")                                                             \
      for (int kk_ = 0; kk_ < 2; ++kk_)                                             \
        a1[mr_][kk_] = *(const bf16x8*)(LB + (PB) + aOff[mr_ + 4][kk_]);            \
    MG(a1, b0, 4, 0)                                                                \
    asm volatile("s_waitcnt lgkmcnt(0)" ::: "memory");                              \
    __builtin_amdgcn_sched_barrier(0);                                              \
    __builtin_amdgcn_s_barrier();                                                   \
    __builtin_amdgcn_sched_barrier(0);                                              \
    stageA(PB, KTN);                                                                \
    MG(a1, b1, 4, 2)                                                                \
    stageB(PB, KTN);                                                                \
    asm volatile("s_waitcnt vmcnt(8)" ::: "memory");                                \
    __builtin_amdgcn_sched_barrier(0);                                              \
    __builtin_amdgcn_s_barrier();                                                   \
    __builtin_amdgcn_sched_barrier(0);                                              \
  }

  // dump accumulators to an act array (frag-linear layout), zero acc
  auto dump = [&](unsigned short* dst, bool gate, float* bg) {
    #pragma unroll
    for (int mr = 0; mr < 8; ++mr)
      #pragma unroll
      for (int nr = 0; nr < 4; ++nr) {
        f32x4 t = acc[mr][nr];
        float e0, e1, e2, e3;
        if (gate) {
          e0 = sigmf(t[0] + bg[nr]); e1 = sigmf(t[1] + bg[nr]);
          e2 = sigmf(t[2] + bg[nr]); e3 = sigmf(t[3] + bg[nr]);
        } else { e0 = t[0]; e1 = t[1]; e2 = t[2]; e3 = t[3]; }
        u32 lo = (u32)f2bf(e0) | ((u32)f2bf(e1) << 16);
        u32 hi = (u32)f2bf(e2) | ((u32)f2bf(e3) << 16);
        size_t F = ((size_t)(((i * 2 + wm) * 8 + mr) * 64 + jj * 16 + wn * 4 + nr)) * 256 + lane * 4;
        uint2 uv; uv.x = lo; uv.y = hi;
        *(uint2*)(dst + F) = uv;
        acc[mr][nr] = (f32x4)(0.0f);
      }
  };

  // prologue: stage tiles 0,1; full drain once
  stageA(0, 0);     stageB(0, 0);
  stageA(32768, 1); stageB(32768, 1);
  asm volatile("s_waitcnt vmcnt(0)" ::: "memory");
  __builtin_amdgcn_s_barrier();
  __builtin_amdgcn_sched_barrier(0);

  // gate GEMM: tiles 0..31
  #pragma unroll 1
  for (int it = 0; it < 16; ++it) {
    int kt = 2 * it;
    TILE(0,     kt,     kt + 2)
    TILE(32768, kt + 1, kt + 3)
  }

  // gate biases + sigmoid + store
  {
    float bg[4];
    #pragma unroll
    for (int nr = 0; nr < 4; ++nr) {
      int gn = jj * 256 + wn * 64 + nr * 16 + r15;
      int np = f ? 1024 + gn : gn;
      bg[nr] = bih[np] + bhh[np];
    }
    dump(f ? actR : actZ, true, bg);
  }

  // act2 GEMM: tiles 32..47
  #pragma unroll 1
  for (int it = 0; it < 8; ++it) {
    int kt = 32 + 2 * it;
    int n0 = kt + 2 <= 47 ? kt + 2 : 47;
    int n1 = kt + 3 <= 47 ? kt + 3 : 47;
    TILE(0,     kt,     n0)
    TILE(32768, kt + 1, n1)
  }

  dump(f ? actH : actC, false, nullptr);
  #undef TILE
  #undef MG
}

// ================= K2: elementwise combine =================
__global__ __launch_bounds__(256) void gru_final(
    const unsigned short* __restrict__ actZ, const unsigned short* __restrict__ actR,
    const unsigned short* __restrict__ actC, const unsigned short* __restrict__ actH,
    const float* __restrict__ Hx, const float* __restrict__ bc,
    const float* __restrict__ bhc, float* __restrict__ out)
{
  int T = blockIdx.x * 256 + threadIdx.x;
  int lane = T & 63, fr = T >> 6;
  int nr = fr & 3, wn = (fr >> 2) & 3, jj = (fr >> 4) & 3, mr = (fr >> 6) & 7, wmI = fr >> 9;
  int n  = jj * 256 + wn * 64 + nr * 16 + (lane & 15);
  int m0 = wmI * 128 + mr * 16 + ((lane >> 4) << 2);
  size_t off = (size_t)T * 4;
  uint2 zq = *(const uint2*)(actZ + off);
  uint2 rq = *(const uint2*)(actR + off);
  uint2 cq = *(const uint2*)(actC + off);
  uint2 hq = *(const uint2*)(actH + off);
  float bcv = bc[n], bhv = bhc[n];
  u32 zw[2] = { zq.x, zq.y }, rw[2] = { rq.x, rq.y };
  u32 cw[2] = { cq.x, cq.y }, hw[2] = { hq.x, hq.y };
  #pragma unroll
  for (int v = 0; v < 4; ++v) {
    int sh = (v & 1) * 16, ix = v >> 1;
    float z = bfu(zw[ix] >> sh);
    float r = bfu(rw[ix] >> sh);
    float c = bfu(cw[ix] >> sh);
    float h = bfu(hw[ix] >> sh);
    size_t adr = (size_t)(m0 + v) * 1024 + n;
    float hx = Hx[adr];
    float cand = tanhf(c + bcv + r * (h + bhv));
    out[adr] = (1.0f - z) * hx + z * cand;
  }
}

// ======== mid-fallback (ws >= 46.1MB): round-1 proven path ========
__global__ __launch_bounds__(256) void cvt_m(
    const float* __restrict__ In, const float* __restrict__ Hx,
    const float* __restrict__ Wih, const float* __restrict__ Whh,
    const float* __restrict__ Wc,  const float* __restrict__ Whc,
    unsigned short* __restrict__ wsIn, unsigned short* __restrict__ wsHx,
    unsigned short* __restrict__ wsWih, unsigned short* __restrict__ wsWhh,
    unsigned short* __restrict__ wsWc,  unsigned short* __restrict__ wsWhc)
{
  int bid = blockIdx.x;
  if (bid < 8192) {
    int gid = bid * 256 + threadIdx.x;
    const float* src; unsigned short* dst; int idx;
    if (gid < (1 << 20)) { src = In; dst = wsIn; idx = gid; }
    else                 { src = Hx; dst = wsHx; idx = gid - (1 << 20); }
    int m = idx >> 7, t = idx & 127;
    const float4* s = (const float4*)(src + (size_t)m * 1024 + t * 8);
    float4 a = s[0], b = s[1];
    int row = m & 127;
    size_t tile = (size_t)(m >> 7) * 32 + (t >> 2);
    int sw = (t & 3) ^ ((row >> 1) & 3);
    bf16x8 v;
    v[0] = (short)f2bf(a.x); v[1] = (short)f2bf(a.y); v[2] = (short)f2bf(a.z); v[3] = (short)f2bf(a.w);
    v[4] = (short)f2bf(b.x); v[5] = (short)f2bf(b.y); v[6] = (short)f2bf(b.z); v[7] = (short)f2bf(b.w);
    *(bf16x8*)(dst + tile * 4096 + row * 32 + sw * 8) = v;
  } else {
    int wb = bid - 8192;
    const float* W; unsigned short* dst; int NW; int local;
    if (wb < 1024)      { W = Wih; dst = wsWih; NW = 2048; local = wb; }
    else if (wb < 2048) { W = Whh; dst = wsWhh; NW = 2048; local = wb - 1024; }
    else if (wb < 2560) { W = Wc;  dst = wsWc;  NW = 1024; local = wb - 2048; }
    else                { W = Whc; dst = wsWhc; NW = 1024; local = wb - 2560; }
    int nb = local >> 5, kb = local & 31;
    int n  = nb * 64 + (threadIdx.x & 63);
    int k0 = kb * 32 + (threadIdx.x >> 6) * 8;
    bf16x8 v;
    #pragma unroll
    for (int b = 0; b < 8; ++b) v[b] = (short)f2bf(W[(size_t)(k0 + b) * NW + n]);
    int row = n & 63;
    size_t tile = (size_t)(n >> 6) * 32 + (k0 >> 5);
    int sw = ((k0 >> 3) & 3) ^ ((row >> 1) & 3);
    *(bf16x8*)(dst + tile * 2048 + row * 32 + sw * 8) = v;
  }
}

__global__ __launch_bounds__(256, 2) void gemm_m(
    const unsigned short* __restrict__ wsIn, const unsigned short* __restrict__ wsHx,
    const unsigned short* __restrict__ wsWih, const unsigned short* __restrict__ wsWhh,
    const unsigned short* __restrict__ wsWc, const unsigned short* __restrict__ wsWhc,
    const float* __restrict__ Hx,
    const float* __restrict__ bih, const float* __restrict__ bhh,
    const float* __restrict__ bc, const float* __restrict__ bhc,
    float* __restrict__ out)
{
  __shared__ unsigned short lds[20480];
  const int tid  = threadIdx.x;
  const int lane = tid & 63;
  const int wave = tid >> 6;
  const int wm = wave >> 1, wn = wave & 1;
  const int bid = blockIdx.x;
  const int j = bid & 15;
  const int i = bid >> 4;
  const unsigned short* srcB[10];
  int strd[10];
  #pragma unroll
  for (int c0 = 0; c0 < 10; ++c0) {
    int c = wave * 10 + c0;
    const unsigned short* p; int st;
    if (c < 8)       { p = wsIn + (size_t)i * 131072 + c * 512;        st = 4096; }
    else if (c < 16) { p = wsHx + (size_t)i * 131072 + (c - 8) * 512;  st = 4096; }
    else {
      int t = (c - 16) >> 2, cc = (c - 16) & 3;
      const unsigned short* base; int nb;
      if (t == 0)      { base = wsWih; nb = j; }
      else if (t == 1) { base = wsWih; nb = j + 16; }
      else if (t == 2) { base = wsWhh; nb = j; }
      else if (t == 3) { base = wsWhh; nb = j + 16; }
      else if (t == 4) { base = wsWc;  nb = j; }
      else             { base = wsWhc; nb = j; }
      p = base + (size_t)nb * 65536 + cc * 512;
      st = 2048;
    }
    srcB[c0] = p + lane * 8;
    strd[c0] = st;
  }
  f32x4 accZ[4][2], accR[4][2], accC[4][2], accH[4][2];
  #pragma unroll
  for (int a = 0; a < 4; ++a)
    #pragma unroll
    for (int b = 0; b < 2; ++b) {
      accZ[a][b] = (f32x4)(0.0f); accR[a][b] = (f32x4)(0.0f);
      accC[a][b] = (f32x4)(0.0f); accH[a][b] = (f32x4)(0.0f);
    }
  const int r15 = lane & 15;
  const int q   = lane >> 4;
  int aOff[4], wOff[2];
  #pragma unroll
  for (int mr = 0; mr < 4; ++mr) {
    int row = wm * 64 + mr * 16 + r15;
    aOff[mr] = row * 32 + ((q ^ ((row >> 1) & 3)) << 3);
  }
  #pragma unroll
  for (int nr = 0; nr < 2; ++nr) {
    int row = wn * 32 + nr * 16 + r15;
    wOff[nr] = row * 32 + ((q ^ ((row >> 1) & 3)) << 3);
  }
  for (int s = 0; s < 32; ++s) {
    __syncthreads();
    #pragma unroll
    for (int c0 = 0; c0 < 10; ++c0)
      gload16((void*)&lds[(wave * 10 + c0) * 512],
              (const void*)(srcB[c0] + (size_t)s * strd[c0]));
    __syncthreads();
    bf16x8 aIn[4], aHx[4];
    #pragma unroll
    for (int mr = 0; mr < 4; ++mr) {
      aIn[mr] = *(const bf16x8*)&lds[aOff[mr]];
      aHx[mr] = *(const bf16x8*)&lds[4096 + aOff[mr]];
    }
    bf16x8 wf[6][2];
    #pragma unroll
    for (int t = 0; t < 6; ++t)
      #pragma unroll
      for (int nr = 0; nr < 2; ++nr)
        wf[t][nr] = *(const bf16x8*)&lds[8192 + t * 2048 + wOff[nr]];
    #pragma unroll
    for (int mr = 0; mr < 4; ++mr)
      #pragma unroll
      for (int nr = 0; nr < 2; ++nr) {
        accZ[mr][nr] = __builtin_amdgcn_mfma_f32_16x16x32_bf16(aIn[mr], wf[0][nr], accZ[mr][nr], 0, 0, 0);
        accZ[mr][nr] = __builtin_amdgcn_mfma_f32_16x16x32_bf16(aHx[mr], wf[2][nr], accZ[mr][nr], 0, 0, 0);
        accR[mr][nr] = __builtin_amdgcn_mfma_f32_16x16x32_bf16(aIn[mr], wf[1][nr], accR[mr][nr], 0, 0, 0);
        accR[mr][nr] = __builtin_amdgcn_mfma_f32_16x16x32_bf16(aHx[mr], wf[3][nr], accR[mr][nr], 0, 0, 0);
        accC[mr][nr] = __builtin_amdgcn_mfma_f32_16x16x32_bf16(aIn[mr], wf[4][nr], accC[mr][nr], 0, 0, 0);
        accH[mr][nr] = __builtin_amdgcn_mfma_f32_16x16x32_bf16(aHx[mr], wf[5][nr], accH[mr][nr], 0, 0, 0);
      }
  }
  const int n0 = j * 64 + wn * 32;
  const int m0 = i * 128 + wm * 64;
  #pragma unroll
  for (int nr = 0; nr < 2; ++nr) {
    int n = n0 + nr * 16 + r15;
    float bz  = bih[n] + bhh[n];
    float br  = bih[1024 + n] + bhh[1024 + n];
    float bcv = bc[n], bhcv = bhc[n];
    #pragma unroll
    for (int mr = 0; mr < 4; ++mr) {
      #pragma unroll
      for (int v = 0; v < 4; ++v) {
        int m = m0 + mr * 16 + q * 4 + v;
        float z  = sigmf(accZ[mr][nr][v] + bz);
        float rr = sigmf(accR[mr][nr][v] + br);
        float cd = tanhf(accC[mr][nr][v] + bcv + rr * (accH[mr][nr][v] + bhcv));
        float h  = Hx[(size_t)m * 1024 + n];
        out[(size_t)m * 1024 + n] = (1.0f - z) * h + z * cd;
      }
    }
  }
}

// ---------------- last-resort fp32 fallback ----------------
__global__ __launch_bounds__(256) void gru_fallback(
    const float* __restrict__ In, const float* __restrict__ Hx,
    const float* __restrict__ Wih, const float* __restrict__ bih,
    const float* __restrict__ Whh, const float* __restrict__ bhh,
    const float* __restrict__ Wc, const float* __restrict__ bc,
    const float* __restrict__ Whc, const float* __restrict__ bhc,
    float* __restrict__ out)
{
  __shared__ float sIn[64][17], sHx[64][17];
  __shared__ float sW[6][16][68];
  const int tid = threadIdx.x;
  const int j = blockIdx.x & 15, i = blockIdx.x >> 4;
  const int tx = tid & 15, ty = tid >> 4;
  float accZ[4][4] = {}, accR[4][4] = {}, accC[4][4] = {}, accH[4][4] = {};
  const int ms = tid >> 2, kq = (tid & 3) * 4;
  const int wk = tid >> 4, wn4 = (tid & 15) * 4;
  for (int k0 = 0; k0 < 1024; k0 += 16) {
    __syncthreads();
    {
      float4 a = *(const float4*)&In[(size_t)(i * 64 + ms) * 1024 + k0 + kq];
      sIn[ms][kq] = a.x; sIn[ms][kq + 1] = a.y; sIn[ms][kq + 2] = a.z; sIn[ms][kq + 3] = a.w;
      float4 b = *(const float4*)&Hx[(size_t)(i * 64 + ms) * 1024 + k0 + kq];
      sHx[ms][kq] = b.x; sHx[ms][kq + 1] = b.y; sHx[ms][kq + 2] = b.z; sHx[ms][kq + 3] = b.w;
    }
    {
      float4 w0 = *(const float4*)&Wih[(size_t)(k0 + wk) * 2048 + j * 64 + wn4];
      float4 w1 = *(const float4*)&Wih[(size_t)(k0 + wk) * 2048 + 1024 + j * 64 + wn4];
      float4 w2 = *(const float4*)&Whh[(size_t)(k0 + wk) * 2048 + j * 64 + wn4];
      float4 w3 = *(const float4*)&Whh[(size_t)(k0 + wk) * 2048 + 1024 + j * 64 + wn4];
      float4 w4 = *(const float4*)&Wc[(size_t)(k0 + wk) * 1024 + j * 64 + wn4];
      float4 w5 = *(const float4*)&Whc[(size_t)(k0 + wk) * 1024 + j * 64 + wn4];
      sW[0][wk][wn4] = w0.x; sW[0][wk][wn4+1] = w0.y; sW[0][wk][wn4+2] = w0.z; sW[0][wk][wn4+3] = w0.w;
      sW[1][wk][wn4] = w1.x; sW[1][wk][wn4+1] = w1.y; sW[1][wk][wn4+2] = w1.z; sW[1][wk][wn4+3] = w1.w;
      sW[2][wk][wn4] = w2.x; sW[2][wk][wn4+1] = w2.y; sW[2][wk][wn4+2] = w2.z; sW[2][wk][wn4+3] = w2.w;
      sW[3][wk][wn4] = w3.x; sW[3][wk][wn4+1] = w3.y; sW[3][wk][wn4+2] = w3.z; sW[3][wk][wn4+3] = w3.w;
      sW[4][wk][wn4] = w4.x; sW[4][wk][wn4+1] = w4.y; sW[4][wk][wn4+2] = w4.z; sW[4][wk][wn4+3] = w4.w;
      sW[5][wk][wn4] = w5.x; sW[5][wk][wn4+1] = w5.y; sW[5][wk][wn4+2] = w5.z; sW[5][wk][wn4+3] = w5.w;
    }
    __syncthreads();
    for (int kk = 0; kk < 16; ++kk) {
      float aI[4], aH[4];
      #pragma unroll
      for (int im = 0; im < 4; ++im) { aI[im] = sIn[ty * 4 + im][kk]; aH[im] = sHx[ty * 4 + im][kk]; }
      #pragma unroll
      for (int jn = 0; jn < 4; ++jn) {
        float w0 = sW[0][kk][tx * 4 + jn], w1 = sW[1][kk][tx * 4 + jn], w2 = sW[2][kk][tx * 4 + jn];
        float w3 = sW[3][kk][tx * 4 + jn], w4 = sW[4][kk][tx * 4 + jn], w5 = sW[5][kk][tx * 4 + jn];
        #pragma unroll
        for (int im = 0; im < 4; ++im) {
          accZ[im][jn] += aI[im] * w0 + aH[im] * w2;
          accR[im][jn] += aI[im] * w1 + aH[im] * w3;
          accC[im][jn] += aI[im] * w4;
          accH[im][jn] += aH[im] * w5;
        }
      }
    }
  }
  #pragma unroll
  for (int jn = 0; jn < 4; ++jn) {
    int n = j * 64 + tx * 4 + jn;
    float bz  = bih[n] + bhh[n];
    float br  = bih[1024 + n] + bhh[1024 + n];
    float bcv = bc[n], bhcv = bhc[n];
    #pragma unroll
    for (int im = 0; im < 4; ++im) {
      int m = i * 64 + ty * 4 + im;
      float z  = sigmf(accZ[im][jn] + bz);
      float rr = sigmf(accR[im][jn] + br);
      float cd = tanhf(accC[im][jn] + bcv + rr * (accH[im][jn] + bhcv));
      float h  = Hx[(size_t)m * 1024 + n];
      out[(size_t)m * 1024 + n] = (1.0f - z) * h + z * cd;
    }
  }
}

extern "C" void kernel_launch(void* const* d_in, const int* in_sizes, int n_in,
                              void* d_out, int out_size, void* d_ws, size_t ws_size,
                              hipStream_t stream) {
  const float* In  = (const float*)d_in[0];
  const float* Hx  = (const float*)d_in[1];
  const float* Wih = (const float*)d_in[2];
  const float* bih = (const float*)d_in[3];
  const float* Whh = (const float*)d_in[4];
  const float* bhh = (const float*)d_in[5];
  const float* Wc  = (const float*)d_in[6];
  const float* bc  = (const float*)d_in[7];
  const float* Whc = (const float*)d_in[8];
  const float* bhc = (const float*)d_in[9];
  float* out = (float*)d_out;

  const size_t WS_BIG = 113246208ull;
  const size_t WS_MID = 46137344ull;
  if (ws_size >= WS_BIG) {
    unsigned short* ws   = (unsigned short*)d_ws;
    unsigned short* wsIn = ws;
    unsigned short* wsHx = ws + 8388608;
    unsigned short* wsW  = ws + 16777216;
    unsigned short* actZ = ws + 23068672;
    unsigned short* actR = ws + 31457280;
    unsigned short* actC = ws + 39845888;
    unsigned short* actH = ws + 48234496;
    cvt2<<<11264, 256, 0, stream>>>(In, Hx, Wih, Whh, Wc, Whc, wsIn, wsHx, wsW);
    gru_gemm1<<<256, 512, 0, stream>>>(wsIn, wsHx, wsW, actZ, actR, actC, actH, bih, bhh);
    gru_final<<<8192, 256, 0, stream>>>(actZ, actR, actC, actH, Hx, bc, bhc, out);
  } else if (ws_size >= WS_MID) {
    unsigned short* ws    = (unsigned short*)d_ws;
    unsigned short* wsIn  = ws;
    unsigned short* wsHx  = ws + 8388608;
    unsigned short* wsWih = ws + 16777216;
    unsigned short* wsWhh = ws + 18874368;
    unsigned short* wsWc  = ws + 20971520;
    unsigned short* wsWhc = ws + 22020096;
    cvt_m<<<11264, 256, 0, stream>>>(In, Hx, Wih, Whh, Wc, Whc,
                                     wsIn, wsHx, wsWih, wsWhh, wsWc, wsWhc);
    gemm_m<<<1024, 256, 0, stream>>>(wsIn, wsHx, wsWih, wsWhh, wsWc, wsWhc,
                                     Hx, bih, bhh, bc, bhc, out);
  } else {
    gru_fallback<<<2048, 256, 0, stream>>>(In, Hx, Wih, bih, Whh, bhh, Wc, bc, Whc, bhc, out);
  }
}

// Round 5
// 133.375 us; speedup vs baseline: 1.1720x; 1.1720x over previous
//
#include <hip/hip_runtime.h>
#include <hip/hip_bf16.h>
#include <cmath>

// GRU cell fused, round 5: single fused GEMM (no act traffic), BM=256 x BN=64,
// 8 waves (4m x 2n), BK=32, 3-phase-per-step m201-style schedule:
//   ph1{read A,w0,w2 | stage other-buf w4w5(t+1) | bar | lgkm0 | 16 MFMA z | bar}
//   ph2{read w1,w3   | stage this-buf A,w0,w2(t+2)| bar | lgkm0 | 16 MFMA r | bar}
//   ph3{read w4,w5   | stage this-buf w1,w3(t+2)  | bar | lgkm0 | 16 MFMA c,h | vmcnt(6) | bar}
// Region-aware same-buffer recycling; vmcnt never drains to 0 in the loop.
// ws layout (ushort elems) — identical to round 1/3 (proven):
//   wsIn  @ 0        : [64 mtile][32 kstep][128x32 swz]
//   wsHx  @ 8388608
//   wsWih @ 16777216 : [32 ntile][32 kstep][64x32 swz]
//   wsWhh @ 18874368
//   wsWc  @ 20971520 : [16 ntile][32 kstep][64x32 swz]
//   wsWhc @ 22020096

typedef __attribute__((ext_vector_type(8))) short bf16x8;
typedef __attribute__((ext_vector_type(4))) float f32x4;
typedef unsigned int u32;

typedef const __attribute__((address_space(1))) u32 gu32;
typedef __attribute__((address_space(3))) u32 su32;

__device__ __forceinline__ unsigned short f2bf(float f) {
  union { float f; u32 u; } v; v.f = f;
  u32 u = v.u;
  u += 0x7FFFu + ((u >> 16) & 1u);   // RTNE
  return (unsigned short)(u >> 16);
}
__device__ __forceinline__ void gload16(void* ldsp, const void* gp) {
  __builtin_amdgcn_global_load_lds((gu32*)gp, (su32*)ldsp, 16, 0, 0);
}
__device__ __forceinline__ float sigmf(float x) { return 1.0f / (1.0f + __expf(-x)); }

#define LGKM0 do { asm volatile("s_waitcnt lgkmcnt(0)" ::: "memory"); __builtin_amdgcn_sched_barrier(0); } while (0)
#define VMC6  do { asm volatile("s_waitcnt vmcnt(6)"   ::: "memory"); __builtin_amdgcn_sched_barrier(0); } while (0)
#define BARR  __builtin_amdgcn_s_barrier()

// ---------------- prepass: fp32 -> bf16 swizzled tiles (proven, unchanged) ----------------
__global__ __launch_bounds__(256) void cvt_all(
    const float* __restrict__ In, const float* __restrict__ Hx,
    const float* __restrict__ Wih, const float* __restrict__ Whh,
    const float* __restrict__ Wc,  const float* __restrict__ Whc,
    unsigned short* __restrict__ wsIn, unsigned short* __restrict__ wsHx,
    unsigned short* __restrict__ wsWih, unsigned short* __restrict__ wsWhh,
    unsigned short* __restrict__ wsWc,  unsigned short* __restrict__ wsWhc)
{
  int bid = blockIdx.x;
  if (bid < 8192) {
    int gid = bid * 256 + threadIdx.x;
    const float* src; unsigned short* dst; int idx;
    if (gid < (1 << 20)) { src = In; dst = wsIn; idx = gid; }
    else                 { src = Hx; dst = wsHx; idx = gid - (1 << 20); }
    int m = idx >> 7, t = idx & 127;
    const float4* s = (const float4*)(src + (size_t)m * 1024 + t * 8);
    float4 a = s[0], b = s[1];
    int row = m & 127;
    size_t tile = (size_t)(m >> 7) * 32 + (t >> 2);
    int sw = (t & 3) ^ ((row >> 1) & 3);
    bf16x8 v;
    v[0] = (short)f2bf(a.x); v[1] = (short)f2bf(a.y); v[2] = (short)f2bf(a.z); v[3] = (short)f2bf(a.w);
    v[4] = (short)f2bf(b.x); v[5] = (short)f2bf(b.y); v[6] = (short)f2bf(b.z); v[7] = (short)f2bf(b.w);
    *(bf16x8*)(dst + tile * 4096 + row * 32 + sw * 8) = v;
  } else {
    int wb = bid - 8192;
    const float* W; unsigned short* dst; int NW; int local;
    if (wb < 1024)      { W = Wih; dst = wsWih; NW = 2048; local = wb; }
    else if (wb < 2048) { W = Whh; dst = wsWhh; NW = 2048; local = wb - 1024; }
    else if (wb < 2560) { W = Wc;  dst = wsWc;  NW = 1024; local = wb - 2048; }
    else                { W = Whc; dst = wsWhc; NW = 1024; local = wb - 2560; }
    int nb = local >> 5, kb = local & 31;
    int n  = nb * 64 + (threadIdx.x & 63);
    int k0 = kb * 32 + (threadIdx.x >> 6) * 8;
    bf16x8 v;
    #pragma unroll
    for (int b = 0; b < 8; ++b) v[b] = (short)f2bf(W[(size_t)(k0 + b) * NW + n]);
    int row = n & 63;
    size_t tile = (size_t)(n >> 6) * 32 + (k0 >> 5);
    int sw = ((k0 >> 3) & 3) ^ ((row >> 1) & 3);
    *(bf16x8*)(dst + tile * 2048 + row * 32 + sw * 8) = v;
  }
}

// ---------------- fused GEMM + GRU epilogue, 3-phase pipeline ----------------
// LDS: 2 buffers x 28672 ushorts (112 KB). Per buffer (ushort offsets):
//   aIn [0,8192) = chunks 0-15 | aHx [8192,16384) = 16-31
//   w0(Wih_z)@16384 c32-35 | w2(Whh_z)@18432 c36-39 | w1(Wih_r)@20480 c40-43
//   w3(Whh_r)@22528 c44-47 | w4(Wc)@24576 c48-51   | w5(Whc)@26624 c52-55
// chunk = 1KB (64 lanes x 16B). Per-wave staging: ph2 -> chunks wave*5..+4,
// ph3 -> 40+wave, ph1 -> 48+wave (of the OTHER buffer, for tile t+1).
__global__ __launch_bounds__(512, 2) void gru_gemm(
    const unsigned short* __restrict__ wsIn, const unsigned short* __restrict__ wsHx,
    const unsigned short* __restrict__ wsWih, const unsigned short* __restrict__ wsWhh,
    const unsigned short* __restrict__ wsWc, const unsigned short* __restrict__ wsWhc,
    const float* __restrict__ Hx,
    const float* __restrict__ bih, const float* __restrict__ bhh,
    const float* __restrict__ bc, const float* __restrict__ bhc,
    float* __restrict__ out)
{
  __shared__ unsigned short lds[57344];
  const int tid  = threadIdx.x;
  const int lane = tid & 63;
  const int wave = tid >> 6;                  // 0..7
  const int wm = wave >> 1, wn = wave & 1;    // 4m x 2n
  const int bid = blockIdx.x;
  const int swz = (bid & 7) * 64 + (bid >> 3);  // bijective XCD swizzle (512 % 8 == 0)
  const int j = swz & 15;                     // n-block (64 cols)
  const int i = swz >> 4;                     // m-block (256 rows)
  const int r15 = lane & 15, q = lane >> 4;

  // ---- chunk source resolver (ws layout) ----
  auto chunkSrc = [&](int c, const unsigned short*& p, int& st) {
    if (c < 16)      { p = wsIn + (size_t)(2 * i + (c >> 3)) * 131072 + (c & 7) * 512; st = 4096; }
    else if (c < 32) { int cc = c - 16; p = wsHx + (size_t)(2 * i + (cc >> 3)) * 131072 + (cc & 7) * 512; st = 4096; }
    else if (c < 36) { p = wsWih + (size_t)j * 65536        + (c - 32) * 512; st = 2048; }
    else if (c < 40) { p = wsWhh + (size_t)j * 65536        + (c - 36) * 512; st = 2048; }
    else if (c < 44) { p = wsWih + (size_t)(j + 16) * 65536 + (c - 40) * 512; st = 2048; }
    else if (c < 48) { p = wsWhh + (size_t)(j + 16) * 65536 + (c - 44) * 512; st = 2048; }
    else if (c < 52) { p = wsWc  + (size_t)j * 65536        + (c - 48) * 512; st = 2048; }
    else             { p = wsWhc + (size_t)j * 65536        + (c - 52) * 512; st = 2048; }
    p += lane * 8;
  };
  const unsigned short* p2[5]; int s2[5];
  #pragma unroll
  for (int k = 0; k < 5; ++k) chunkSrc(wave * 5 + k, p2[k], s2[k]);
  const unsigned short* p3; int s3; chunkSrc(40 + wave, p3, s3);
  const unsigned short* p1; int s1; chunkSrc(48 + wave, p1, s1);
  const int d2 = wave * 5 * 512;
  const int d3 = (40 + wave) * 512;
  const int d1 = (48 + wave) * 512;

  f32x4 accZ[4][2], accR[4][2], accC[4][2], accH[4][2];
  #pragma unroll
  for (int a = 0; a < 4; ++a)
    #pragma unroll
    for (int b = 0; b < 2; ++b) {
      accZ[a][b] = (f32x4)(0.0f); accR[a][b] = (f32x4)(0.0f);
      accC[a][b] = (f32x4)(0.0f); accH[a][b] = (f32x4)(0.0f);
    }

  int aOff[4], wOff[2];
  #pragma unroll
  for (int mr = 0; mr < 4; ++mr) {
    int gr = wm * 64 + mr * 16 + r15;         // 0..255
    aOff[mr] = (gr >> 7) * 4096 + (gr & 127) * 32 + ((q ^ ((gr >> 1) & 3)) << 3);
  }
  #pragma unroll
  for (int nr = 0; nr < 2; ++nr) {
    int wr = wn * 32 + nr * 16 + r15;         // 0..63
    wOff[nr] = wr * 32 + ((q ^ ((wr >> 1) & 3)) << 3);
  }

  #define MFMA16(AI, AH, WA, WB, ACC)                                                \
    __builtin_amdgcn_s_setprio(1);                                                   \
    _Pragma("unroll")                                                                \
    for (int mr_ = 0; mr_ < 4; ++mr_)                                                \
      _Pragma("unroll")                                                              \
      for (int nr_ = 0; nr_ < 2; ++nr_) {                                            \
        ACC[mr_][nr_] = __builtin_amdgcn_mfma_f32_16x16x32_bf16(AI[mr_], WA[nr_], ACC[mr_][nr_], 0, 0, 0); \
        ACC[mr_][nr_] = __builtin_amdgcn_mfma_f32_16x16x32_bf16(AH[mr_], WB[nr_], ACC[mr_][nr_], 0, 0, 0); \
      }                                                                              \
    __builtin_amdgcn_s_setprio(0);

  auto step = [&](int B, int OB, int sP1, int sP23) {
    bf16x8 aIn[4], aHx[4], wA[2], wB[2];
    // ---------- ph1: z ----------
    #pragma unroll
    for (int mr = 0; mr < 4; ++mr) {
      aIn[mr] = *(const bf16x8*)&lds[B + aOff[mr]];
      aHx[mr] = *(const bf16x8*)&lds[B + 8192 + aOff[mr]];
    }
    #pragma unroll
    for (int nr = 0; nr < 2; ++nr) {
      wA[nr] = *(const bf16x8*)&lds[B + 16384 + wOff[nr]];   // w0 = Wih_z
      wB[nr] = *(const bf16x8*)&lds[B + 18432 + wOff[nr]];   // w2 = Whh_z
    }
    gload16((void*)&lds[OB + d1], (const void*)(p1 + (size_t)sP1 * s1)); // t+1 w4w5
    BARR;
    LGKM0;
    MFMA16(aIn, aHx, wA, wB, accZ)
    BARR;
    // ---------- ph2: r ----------
    #pragma unroll
    for (int nr = 0; nr < 2; ++nr) {
      wA[nr] = *(const bf16x8*)&lds[B + 20480 + wOff[nr]];   // w1 = Wih_r
      wB[nr] = *(const bf16x8*)&lds[B + 22528 + wOff[nr]];   // w3 = Whh_r
    }
    #pragma unroll
    for (int k = 0; k < 5; ++k)
      gload16((void*)&lds[B + d2 + k * 512], (const void*)(p2[k] + (size_t)sP23 * s2[k])); // t+2 A,w0,w2
    BARR;
    LGKM0;
    MFMA16(aIn, aHx, wA, wB, accR)
    BARR;
    // ---------- ph3: c,h ----------
    #pragma unroll
    for (int nr = 0; nr < 2; ++nr) {
      wA[nr] = *(const bf16x8*)&lds[B + 24576 + wOff[nr]];   // w4 = Wc
      wB[nr] = *(const bf16x8*)&lds[B + 26624 + wOff[nr]];   // w5 = Whc
    }
    gload16((void*)&lds[B + d3], (const void*)(p3 + (size_t)sP23 * s3)); // t+2 w1w3
    BARR;
    LGKM0;
    __builtin_amdgcn_s_setprio(1);
    #pragma unroll
    for (int mr_ = 0; mr_ < 4; ++mr_)
      #pragma unroll
      for (int nr_ = 0; nr_ < 2; ++nr_) {
        accC[mr_][nr_] = __builtin_amdgcn_mfma_f32_16x16x32_bf16(aIn[mr_], wA[nr_], accC[mr_][nr_], 0, 0, 0);
        accH[mr_][nr_] = __builtin_amdgcn_mfma_f32_16x16x32_bf16(aHx[mr_], wB[nr_], accH[mr_][nr_], 0, 0, 0);
      }
    __builtin_amdgcn_s_setprio(0);
    VMC6;          // everything except this step's ph2(5)+ph3(1) has landed
    BARR;
  };

  // ---------- prologue: tile0 full -> buf0, tile1 minus w4w5 -> buf1 ----------
  #pragma unroll
  for (int k = 0; k < 5; ++k) gload16((void*)&lds[d2 + k * 512], (const void*)p2[k]);
  gload16((void*)&lds[d3], (const void*)p3);
  gload16((void*)&lds[d1], (const void*)p1);
  #pragma unroll
  for (int k = 0; k < 5; ++k) gload16((void*)&lds[28672 + d2 + k * 512], (const void*)(p2[k] + s2[k]));
  gload16((void*)&lds[28672 + d3], (const void*)(p3 + s3));
  VMC6;            // tile0's 7 chunks landed; tile1's 6 stay in flight
  BARR;

  // ---------- main loop: 32 K-steps ----------
  #pragma unroll 1
  for (int it = 0; it < 16; ++it) {
    const int s = 2 * it;
    step(0,     28672, s + 1 <= 31 ? s + 1 : 31, s + 2 <= 31 ? s + 2 : 31);
    step(28672, 0,     s + 2 <= 31 ? s + 2 : 31, s + 3 <= 31 ? s + 3 : 31);
  }
  #undef MFMA16

  // ---------- epilogue (proven round-3 layout) ----------
  const int n0 = j * 64 + wn * 32;
  const int m0 = i * 256 + wm * 64;
  #pragma unroll
  for (int nr = 0; nr < 2; ++nr) {
    int n = n0 + nr * 16 + r15;
    float bz  = bih[n] + bhh[n];
    float br  = bih[1024 + n] + bhh[1024 + n];
    float bcv = bc[n], bhcv = bhc[n];
    #pragma unroll
    for (int mr = 0; mr < 4; ++mr) {
      #pragma unroll
      for (int v = 0; v < 4; ++v) {
        int m = m0 + mr * 16 + q * 4 + v;
        float z  = sigmf(accZ[mr][nr][v] + bz);
        float rr = sigmf(accR[mr][nr][v] + br);
        float cd = tanhf(accC[mr][nr][v] + bcv + rr * (accH[mr][nr][v] + bhcv));
        float h  = Hx[(size_t)m * 1024 + n];
        out[(size_t)m * 1024 + n] = (1.0f - z) * h + z * cd;
      }
    }
  }
}

// ---------------- last-resort fp32 fallback ----------------
__global__ __launch_bounds__(256) void gru_fallback(
    const float* __restrict__ In, const float* __restrict__ Hx,
    const float* __restrict__ Wih, const float* __restrict__ bih,
    const float* __restrict__ Whh, const float* __restrict__ bhh,
    const float* __restrict__ Wc, const float* __restrict__ bc,
    const float* __restrict__ Whc, const float* __restrict__ bhc,
    float* __restrict__ out)
{
  __shared__ float sIn[64][17], sHx[64][17];
  __shared__ float sW[6][16][68];
  const int tid = threadIdx.x;
  const int j = blockIdx.x & 15, i = blockIdx.x >> 4;
  const int tx = tid & 15, ty = tid >> 4;
  float accZ[4][4] = {}, accR[4][4] = {}, accC[4][4] = {}, accH[4][4] = {};
  const int ms = tid >> 2, kq = (tid & 3) * 4;
  const int wk = tid >> 4, wn4 = (tid & 15) * 4;
  for (int k0 = 0; k0 < 1024; k0 += 16) {
    __syncthreads();
    {
      float4 a = *(const float4*)&In[(size_t)(i * 64 + ms) * 1024 + k0 + kq];
      sIn[ms][kq] = a.x; sIn[ms][kq + 1] = a.y; sIn[ms][kq + 2] = a.z; sIn[ms][kq + 3] = a.w;
      float4 b = *(const float4*)&Hx[(size_t)(i * 64 + ms) * 1024 + k0 + kq];
      sHx[ms][kq] = b.x; sHx[ms][kq + 1] = b.y; sHx[ms][kq + 2] = b.z; sHx[ms][kq + 3] = b.w;
    }
    {
      float4 w0 = *(const float4*)&Wih[(size_t)(k0 + wk) * 2048 + j * 64 + wn4];
      float4 w1 = *(const float4*)&Wih[(size_t)(k0 + wk) * 2048 + 1024 + j * 64 + wn4];
      float4 w2 = *(const float4*)&Whh[(size_t)(k0 + wk) * 2048 + j * 64 + wn4];
      float4 w3 = *(const float4*)&Whh[(size_t)(k0 + wk) * 2048 + 1024 + j * 64 + wn4];
      float4 w4 = *(const float4*)&Wc[(size_t)(k0 + wk) * 1024 + j * 64 + wn4];
      float4 w5 = *(const float4*)&Whc[(size_t)(k0 + wk) * 1024 + j * 64 + wn4];
      sW[0][wk][wn4] = w0.x; sW[0][wk][wn4+1] = w0.y; sW[0][wk][wn4+2] = w0.z; sW[0][wk][wn4+3] = w0.w;
      sW[1][wk][wn4] = w1.x; sW[1][wk][wn4+1] = w1.y; sW[1][wk][wn4+2] = w1.z; sW[1][wk][wn4+3] = w1.w;
      sW[2][wk][wn4] = w2.x; sW[2][wk][wn4+1] = w2.y; sW[2][wk][wn4+2] = w2.z; sW[2][wk][wn4+3] = w2.w;
      sW[3][wk][wn4] = w3.x; sW[3][wk][wn4+1] = w3.y; sW[3][wk][wn4+2] = w3.z; sW[3][wk][wn4+3] = w3.w;
      sW[4][wk][wn4] = w4.x; sW[4][wk][wn4+1] = w4.y; sW[4][wk][wn4+2] = w4.z; sW[4][wk][wn4+3] = w4.w;
      sW[5][wk][wn4] = w5.x; sW[5][wk][wn4+1] = w5.y; sW[5][wk][wn4+2] = w5.z; sW[5][wk][wn4+3] = w5.w;
    }
    __syncthreads();
    for (int kk = 0; kk < 16; ++kk) {
      float aI[4], aH[4];
      #pragma unroll
      for (int im = 0; im < 4; ++im) { aI[im] = sIn[ty * 4 + im][kk]; aH[im] = sHx[ty * 4 + im][kk]; }
      #pragma unroll
      for (int jn = 0; jn < 4; ++jn) {
        float w0 = sW[0][kk][tx * 4 + jn], w1 = sW[1][kk][tx * 4 + jn], w2 = sW[2][kk][tx * 4 + jn];
        float w3 = sW[3][kk][tx * 4 + jn], w4 = sW[4][kk][tx * 4 + jn], w5 = sW[5][kk][tx * 4 + jn];
        #pragma unroll
        for (int im = 0; im < 4; ++im) {
          accZ[im][jn] += aI[im] * w0 + aH[im] * w2;
          accR[im][jn] += aI[im] * w1 + aH[im] * w3;
          accC[im][jn] += aI[im] * w4;
          accH[im][jn] += aH[im] * w5;
        }
      }
    }
  }
  #pragma unroll
  for (int jn = 0; jn < 4; ++jn) {
    int n = j * 64 + tx * 4 + jn;
    float bz  = bih[n] + bhh[n];
    float br  = bih[1024 + n] + bhh[1024 + n];
    float bcv = bc[n], bhcv = bhc[n];
    #pragma unroll
    for (int im = 0; im < 4; ++im) {
      int m = i * 64 + ty * 4 + im;
      float z  = sigmf(accZ[im][jn] + bz);
      float rr = sigmf(accR[im][jn] + br);
      float cd = tanhf(accC[im][jn] + bcv + rr * (accH[im][jn] + bhcv));
      float h  = Hx[(size_t)m * 1024 + n];
      out[(size_t)m * 1024 + n] = (1.0f - z) * h + z * cd;
    }
  }
}

extern "C" void kernel_launch(void* const* d_in, const int* in_sizes, int n_in,
                              void* d_out, int out_size, void* d_ws, size_t ws_size,
                              hipStream_t stream) {
  const float* In  = (const float*)d_in[0];
  const float* Hx  = (const float*)d_in[1];
  const float* Wih = (const float*)d_in[2];
  const float* bih = (const float*)d_in[3];
  const float* Whh = (const float*)d_in[4];
  const float* bhh = (const float*)d_in[5];
  const float* Wc  = (const float*)d_in[6];
  const float* bc  = (const float*)d_in[7];
  const float* Whc = (const float*)d_in[8];
  const float* bhc = (const float*)d_in[9];
  float* out = (float*)d_out;

  const size_t WS_NEED = 46137344ull;
  if (ws_size >= WS_NEED) {
    unsigned short* ws    = (unsigned short*)d_ws;
    unsigned short* wsIn  = ws;
    unsigned short* wsHx  = ws + 8388608;
    unsigned short* wsWih = ws + 16777216;
    unsigned short* wsWhh = ws + 18874368;
    unsigned short* wsWc  = ws + 20971520;
    unsigned short* wsWhc = ws + 22020096;
    cvt_all<<<11264, 256, 0, stream>>>(In, Hx, Wih, Whh, Wc, Whc,
                                       wsIn, wsHx, wsWih, wsWhh, wsWc, wsWhc);
    gru_gemm<<<512, 512, 0, stream>>>(wsIn, wsHx, wsWih, wsWhh, wsWc, wsWhc,
                                      Hx, bih, bhh, bc, bhc, out);
  } else {
    gru_fallback<<<2048, 256, 0, stream>>>(In, Hx, Wih, bih, Whh, bhh, Wc, bc, Whc, bhc, out);
  }
}